// Round 3
// baseline (215.281 us; speedup 1.0000x reference)
//
#include <hip/hip_runtime.h>
#include <math.h>

#define KNN_EPS 1e-8f
// Spatial grid: domain [0,256)^3, cell h=16 -> 16^3 = 4096 cells.
#define GH 16.0f
#define GC 16
#define NCELLS (GC * GC * GC)
#define MARGIN 1.0f   // >> max |noisy_d - true_d| (~0.05) -> safe pruning
#define CAPR 16       // ref bucket slots/cell. Poisson(4.88): P(>16)~1e-5 ->
                      // ~0.05 expected spilled refs/run; spills go to the
                      // global refspill list evaluated by every query (same
                      // candidate union as before -> bit-identical output).
                      // rbuck = 4096*16*16B = 1 MB: fits ONE XCD L2.

// ---------------------------------------------------------------------------
// Validated arithmetic (round 8, absmax 0.0547):
//   rsq/qsq: non-fused sequential squares; t: asc FMA chain;
//   d = max(fma(-2,t,fl(qsq+rsq)), 0); epilogue: +eps, IEEE div, seq sums.
// Selection: (d, idx) lexicographic min-3 -- order-independent, bit-identical
// across r10-r17 restructures (scan order is harmless).
// DO NOT change roundings -- only execution structure.
//
// r17: the r13-r16 invariant 90-110us was the SPARSE BUCKET HANDOFF, not
// compute: scatter write-allocate dirtied ~12MB of qbuck lines; knn re-read
// them through cross-XCD eviction (WRITE_SIZE 7-15MB >> 640KB of out).
//  -> qbuck DELETED: search recomputes queries bit-identically from
//     xyz2+motion (streaming 2.2MB, coalesced). qspill kernel gone.
//  -> CAPR 64->16: rbuck 4MB->1MB, L2-resident.
//  -> query-parallel search: lane=query, 4 slabs of the 27-hood per block,
//     10k waves (vs 4096) for TLP; LDS partial merge (INF-guarded lex).
// ---------------------------------------------------------------------------

__device__ __forceinline__ int cell_coord(float v) {
    int c = (int)floorf(v * (1.0f / GH));
    return min(max(c, 0), GC - 1);
}

// Scatter ONLY the reference points (20k) into compact buckets.
__global__ void scatter_ref_kernel(
    const float* __restrict__ xyz1, int n1,
    int* __restrict__ counts,
    float4* __restrict__ rbuck,
    float4* __restrict__ refspill, int* __restrict__ rsn)
{
#pragma clang fp contract(off)
    int i = blockIdx.x * blockDim.x + threadIdx.x;
    if (i >= n1) return;
    float x = xyz1[3 * i + 0];
    float y = xyz1[3 * i + 1];
    float z = xyz1[3 * i + 2];
    int cid = (cell_coord(z) * GC + cell_coord(y)) * GC + cell_coord(x);
    int pos = atomicAdd(&counts[cid], 1);
    float4 v = make_float4(x, y, z, __int_as_float(i));
    if (pos < CAPR) rbuck[cid * CAPR + pos] = v;
    else { int sp = atomicAdd(rsn, 1); refspill[sp] = v; }
}

// (d, idx)-lexicographic insert: order-independent == validated stable scan.
__device__ __forceinline__ void top3_insert_lex(float d, int j,
                                                float& bd0, float& bd1, float& bd2,
                                                int& bi0, int& bi1, int& bi2) {
    if (d < bd2 || (d == bd2 && j < bi2)) {
        if (d < bd1 || (d == bd1 && j < bi1)) {
            bd2 = bd1; bi2 = bi1;
            if (d < bd0 || (d == bd0 && j < bi0)) {
                bd1 = bd0; bi1 = bi0;
                bd0 = d;   bi0 = j;
            } else {
                bd1 = d;   bi1 = j;
            }
        } else {
            bd2 = d;       bi2 = j;
        }
    }
}

// Validated candidate evaluation (round 8 roundings, rsq recomputed bit-equal)
__device__ __forceinline__ void eval_candidate(
    float4 r, float qx, float qy, float qz, float qsq,
    float& bd0, float& bd1, float& bd2, int& bi0, int& bi1, int& bi2) {
    int ridx = __float_as_int(r.w);
    float rsq = r.x * r.x + r.y * r.y;
    rsq = rsq + r.z * r.z;
    float t = fmaf(qz, r.z, fmaf(qy, r.y, qx * r.x));
    float h = qsq + rsq;
    float d = fmaxf(fmaf(-2.0f, t, h), 0.0f);
    top3_insert_lex(d, ridx, bd0, bd1, bd2, bi0, bi1, bi2);
}

// Rigorous certification radius after scanning cell-rings <= rho.
__device__ __forceinline__ float cert_radius(float qx, float qy, float qz,
                                             int icx, int icy, int icz, int rho) {
    float R = INFINITY;
    if (icx - rho > 0)      R = fminf(R, qx - (float)(icx - rho) * GH);
    if (icx + rho < GC - 1) R = fminf(R, (float)(icx + rho + 1) * GH - qx);
    if (icy - rho > 0)      R = fminf(R, qy - (float)(icy - rho) * GH);
    if (icy + rho < GC - 1) R = fminf(R, (float)(icy + rho + 1) * GH - qy);
    if (icz - rho > 0)      R = fminf(R, qz - (float)(icz - rho) * GH);
    if (icz + rho < GC - 1) R = fminf(R, (float)(icz + rho + 1) * GH - qz);
    return R;
}

// Validated epilogue (round 8) -> writes out[qid]
__device__ __forceinline__ void epilogue_store(
    float bd0, float bd1, float bd2, int bi0, int bi1, int bi2,
    int qid, int C, const float* __restrict__ point1, float* __restrict__ out) {
#pragma clang fp contract(off)
    float dd0 = bd0 + KNN_EPS;
    float dd1 = bd1 + KNN_EPS;
    float dd2 = bd2 + KNN_EPS;
    float w0 = 1.0f / dd0;
    float w1 = 1.0f / dd1;
    float w2 = 1.0f / dd2;
    float s  = w0 + w1;
    s = s + w2;
    float m = fmaxf(s, 3.0f);
    w0 = w0 / m;
    w1 = w1 / m;
    w2 = w2 / m;
    const int c = qid - (qid / C) * C;
    float p0 = point1[bi0 * C + c];
    float p1 = point1[bi1 * C + c];
    float p2 = point1[bi2 * C + c];
    float acc = w0 * p0 + w1 * p1;
    acc = acc + w2 * p2;
    out[qid] = acc;
}

// r17 search: one LANE per query, 4 slabs of the 27-cell neighborhood per
// 256-thread block (slab = tid>>6; slab 3 gets 6 cells + the refspill list).
// Counts prefetched up-front (one latency window); candidate gathers are
// L2-resident (rbuck 1MB). Partial top-3s merged via LDS with the validated
// INF-guarded lexicographic insert. Slab 0 does cert / rare fallback /
// epilogue. Candidate set per query == 27-hood rbuck U refspill == previous
// rounds -> bit-identical output.
__global__ __launch_bounds__(256, 4) void knn_query_kernel(
    const float* __restrict__ xyz2,
    const float* __restrict__ motion,
    const float4* __restrict__ rbuck,
    const int*   __restrict__ counts,
    const float4* __restrict__ refspill,
    const int*   __restrict__ rsn,
    const float* __restrict__ point1,
    float* __restrict__ out,
    int nq, int C)
{
#pragma clang fp contract(off)
    const int tid  = threadIdx.x;
    const int lane = tid & 63;
    const int slab = tid >> 6;          // wave-uniform
    const int qi   = blockIdx.x * 64 + lane;
    const bool active = qi < nq;
    const int i = active ? qi : 0;
    const int n = i / C;

    // bit-identical query recompute (validated adds, contract off)
    const float qx = xyz2[3 * n + 0] + motion[3 * i + 0];
    const float qy = xyz2[3 * n + 1] + motion[3 * i + 1];
    const float qz = xyz2[3 * n + 2] + motion[3 * i + 2];
    float qsq = qx * qx + qy * qy;
    qsq = qsq + qz * qz;

    const int icx = cell_coord(qx);
    const int icy = cell_coord(qy);
    const int icz = cell_coord(qz);

    float bd0 = INFINITY, bd1 = INFINITY, bd2 = INFINITY;
    int   bi0 = 0,        bi1 = 0,        bi2 = 0;

    // ---- prefetch my slab's neighbor counts (7 independent loads) ----
    int es[7];
#pragma unroll
    for (int rr = 0; rr < 7; ++rr) {
        const int r = slab * 7 + rr;
        int e = 0;
        if (r < 27) {
            const int dz = r / 9 - 1, dy = (r / 3) % 3 - 1, dx = r % 3 - 1;
            const int cz = icz + dz, cy = icy + dy, cx = icx + dx;
            if ((unsigned)cz < GC && (unsigned)cy < GC && (unsigned)cx < GC) {
                const int cid = (cz * GC + cy) * GC + cx;
                e = min(counts[cid], CAPR);
            }
        }
        es[rr] = e;
    }

    // ---- scan my slab's cells (per-lane gathers, L2-resident rbuck) ----
#pragma unroll
    for (int rr = 0; rr < 7; ++rr) {
        const int r = slab * 7 + rr;
        if (r < 27) {
            const int e = es[rr];
            if (e > 0) {
                const int dz = r / 9 - 1, dy = (r / 3) % 3 - 1, dx = r % 3 - 1;
                const int cid = ((icz + dz) * GC + (icy + dy)) * GC + (icx + dx);
                const float4* __restrict__ cp = rbuck + cid * CAPR;
                for (int s = 0; s < e; ++s)
                    eval_candidate(cp[s], qx, qy, qz, qsq,
                                   bd0, bd1, bd2, bi0, bi1, bi2);
            }
        }
    }

    // slab 3 also evaluates the global refspill list (~never non-empty)
    if (slab == 3) {
        const int rspn = *rsn;
        for (int k = 0; k < rspn; ++k)
            eval_candidate(refspill[k], qx, qy, qz, qsq,
                           bd0, bd1, bd2, bi0, bi1, bi2);
    }

    // ---- merge partials (slabs 1..3 -> LDS; slab 0 merges) ----
    __shared__ float pbd[3][64][3];
    __shared__ int   pbi[3][64][3];
    if (slab > 0) {
        pbd[slab - 1][lane][0] = bd0; pbi[slab - 1][lane][0] = bi0;
        pbd[slab - 1][lane][1] = bd1; pbi[slab - 1][lane][1] = bi1;
        pbd[slab - 1][lane][2] = bd2; pbi[slab - 1][lane][2] = bi2;
    }
    __syncthreads();

    if (slab == 0) {
#pragma unroll
        for (int sl = 0; sl < 3; ++sl)
#pragma unroll
            for (int m = 0; m < 3; ++m) {
                float d = pbd[sl][lane][m];
                if (d < INFINITY)   // INF guard: empty partial slots must not insert
                    top3_insert_lex(d, pbi[sl][lane][m],
                                    bd0, bd1, bd2, bi0, bi1, bi2);
            }

        // Certified after full rho<=1 ring (+spill); fallback ~1e-6.
        float R = cert_radius(qx, qy, qz, icx, icy, icz, 1);
        if (!(bd2 + MARGIN <= R * R)) {
            for (int rho = 2; rho < GC; ++rho) {
                for (int dz = -rho; dz <= rho; ++dz) {
                    int cz = icz + dz;
                    if (cz < 0 || cz >= GC) continue;
                    int adz = (dz < 0) ? -dz : dz;
                    for (int dy = -rho; dy <= rho; ++dy) {
                        int cy = icy + dy;
                        if (cy < 0 || cy >= GC) continue;
                        int ady = (dy < 0) ? -dy : dy;
                        int step = (adz == rho || ady == rho) ? 1 : 2 * rho;
                        for (int dx = -rho; dx <= rho; dx += step) {
                            int cx = icx + dx;
                            if (cx < 0 || cx >= GC) continue;
                            int cid = (cz * GC + cy) * GC + cx;
                            int e = min(counts[cid], CAPR);
                            for (int s = 0; s < e; ++s)
                                eval_candidate(rbuck[cid * CAPR + s],
                                               qx, qy, qz, qsq,
                                               bd0, bd1, bd2, bi0, bi1, bi2);
                        }
                    }
                }
                float Rr = cert_radius(qx, qy, qz, icx, icy, icz, rho);
                if (bd2 + MARGIN <= Rr * Rr) break;
            }
        }

        if (active)
            epilogue_store(bd0, bd1, bd2, bi0, bi1, bi2, qi, C, point1, out);
    }
}

extern "C" void kernel_launch(void* const* d_in, const int* in_sizes, int n_in,
                              void* d_out, int out_size, void* d_ws, size_t ws_size,
                              hipStream_t stream) {
    const float* xyz1   = (const float*)d_in[0];
    const float* point1 = (const float*)d_in[1];
    const float* xyz2   = (const float*)d_in[2];
    const float* motion = (const float*)d_in[3];
    float* out = (float*)d_out;

    const int n1 = in_sizes[0] / 3;
    const int n2 = in_sizes[2] / 3;
    const int C  = in_sizes[1] / n1;
    const int nq = n2 * C;

    // ws layout (~1.4 MB): rbuck | refspill | zero-zone(counts, rsn)
    char* ws = (char*)d_ws;
    size_t off = 0;
    auto alloc = [&](size_t bytes) {
        char* p = ws + off;
        off = (off + bytes + 255) & ~(size_t)255;
        return p;
    };
    float4* rbuck    = (float4*)alloc((size_t)NCELLS * CAPR * 16);
    float4* refspill = (float4*)alloc((size_t)n1 * 16);
    int*    zero     = (int*)alloc((size_t)(NCELLS + 1) * 4);
    int* counts = zero;
    int* rsn    = zero + NCELLS;

    hipMemsetAsync(zero, 0, (size_t)(NCELLS + 1) * 4, stream);
    scatter_ref_kernel<<<(n1 + 255) / 256, 256, 0, stream>>>(
        xyz1, n1, counts, rbuck, refspill, rsn);
    knn_query_kernel<<<(nq + 63) / 64, 256, 0, stream>>>(
        xyz2, motion, rbuck, counts, refspill, rsn, point1, out, nq, C);
}